// Round 13
// baseline (3332.037 us; speedup 1.0000x reference)
//
#include <hip/hip_runtime.h>
#include <hip/hip_bf16.h>

// ---------------------------------------------------------------------------
// DiT forward, bf16-MFMA implementation.
// B=32, IMG=32, CIN=4, PATCH=2, HIDDEN=768, DEPTH=12, HEADS=12 (dh=64),
// MLP=3072, N=256 tokens, rows = B*N = 8192.
// ---------------------------------------------------------------------------

typedef short  s16x8 __attribute__((ext_vector_type(8)));
typedef float  f32x4 __attribute__((ext_vector_type(4)));

__device__ __forceinline__ float bf2f(unsigned short u) {
    union { unsigned int i; float f; } v; v.i = ((unsigned int)u) << 16; return v.f;
}
__device__ __forceinline__ unsigned short f2bf(float f) {
    union { float f; unsigned int i; } v; v.f = f;
    unsigned int r = (v.i + 0x7FFFu + ((v.i >> 16) & 1u)) >> 16;
    return (unsigned short)r;
}
__device__ __forceinline__ float silu(float v) { return v / (1.f + __expf(-v)); }

// async global->LDS, 16B per lane. Global addr is PER-LANE; LDS dest is
// wave-uniform base, HW writes lane i at base + i*16B. [m97/m104]
__device__ __forceinline__ void gload16(const void* gptr, void* lptr) {
    __builtin_amdgcn_global_load_lds(
        (const __attribute__((address_space(1))) unsigned int*)gptr,
        (__attribute__((address_space(3))) unsigned int*)lptr,
        16, 0, 0);
}

#define ROWS 8192
#define HID  768
#define MLPD 3072
#define ADA_LD 4608

// ---------------------------------------------------------------------------
// Kernel 0: init targets. bid0=222 (grid 3): z1/z2 only (big path).
// bid0=0 (grid 225): also bias-init ada/fada for the atomic fallback path.
// ---------------------------------------------------------------------------
__global__ __launch_bounds__(256) void ada_init(const float* __restrict__ ada_b,
                                                const float* __restrict__ fada_b,
                                                const float* __restrict__ t_b1,
                                                const float* __restrict__ t_b2,
                                                const float* __restrict__ lemb,
                                                const int* __restrict__ y,
                                                float* __restrict__ ada_all,
                                                float* __restrict__ fada,
                                                float* __restrict__ z1,
                                                float* __restrict__ z2,
                                                int bid0)
{
    const int bid = blockIdx.x + bid0, tid = threadIdx.x;
    if (bid >= 222) {
        const int col = (bid - 222) * 256 + tid;
        const float b1v = t_b1[col], b2v = t_b2[col];
        for (int r = 0; r < 32; ++r) {
            z1[(size_t)r * HID + col] = b1v;
            z2[(size_t)r * HID + col] = b2v + lemb[(size_t)y[r] * HID + col];
        }
        return;
    }
    const float* Bv; float* Out; int ldw, colb;
    if (bid < 216) {
        const int l = bid / 18; colb = (bid % 18) * 256;
        Bv = ada_b + (size_t)l * ADA_LD; Out = ada_all + (size_t)l * 32 * ADA_LD; ldw = ADA_LD;
    } else {
        colb = (bid - 216) * 256;
        Bv = fada_b; Out = fada; ldw = 1536;
    }
    const int col = colb + tid;
    const float bb = Bv[col];
    #pragma unroll
    for (int r = 0; r < 32; ++r) Out[(size_t)r * ldw + col] = bb;
}

// ---------------------------------------------------------------------------
// Kernel 1: timestep embedding stage 1 (k-split), grid (32, 3, 2)
// ---------------------------------------------------------------------------
__global__ __launch_bounds__(256) void temb1_k(const float* __restrict__ t,
                                               const float* __restrict__ w1,
                                               float* __restrict__ z1)
{
    __shared__ float tin[128];
    const int b = blockIdx.x, cc = blockIdx.y, kc = blockIdx.z, tid = threadIdx.x;
    const int k0 = kc * 128;
    if (tid < 128) {
        const int k = k0 + tid, j = k & 127;
        const float fr = __expf((float)j * (-9.210340371976184f / 128.f));
        const float a = t[b] * fr;
        tin[tid] = (k < 128) ? cosf(a) : sinf(a);
    }
    __syncthreads();
    const int col = cc * 256 + tid;
    float acc = 0.f;
    #pragma unroll 8
    for (int kk = 0; kk < 128; ++kk) acc += tin[kk] * w1[(size_t)(k0 + kk) * HID + col];
    atomicAdd(&z1[(size_t)b * HID + col], acc);
}

// ---------------------------------------------------------------------------
// Kernel 2: stage 2 (k-split), grid (32, 3, 4)
// ---------------------------------------------------------------------------
__global__ __launch_bounds__(256) void temb2_k(const float* __restrict__ z1,
                                               const float* __restrict__ w2,
                                               float* __restrict__ z2)
{
    __shared__ float tin[192];
    const int b = blockIdx.x, cc = blockIdx.y, kc = blockIdx.z, tid = threadIdx.x;
    const int k0 = kc * 192;
    if (tid < 192) tin[tid] = silu(z1[(size_t)b * HID + k0 + tid]);
    __syncthreads();
    const int col = cc * 256 + tid;
    float acc = 0.f;
    #pragma unroll 8
    for (int kk = 0; kk < 192; ++kk) acc += tin[kk] * w2[(size_t)(k0 + kk) * HID + col];
    atomicAdd(&z2[(size_t)b * HID + col], acc);
}

// ---------------------------------------------------------------------------
// Kernel 2b: cact_bf = bf16(silu(z2))  [32][768]
// ---------------------------------------------------------------------------
__global__ __launch_bounds__(256) void csilu_k(const float* __restrict__ z2,
                                               unsigned short* __restrict__ cact_bf)
{
    const int base = (blockIdx.x * 256 + threadIdx.x) * 8;
    #pragma unroll
    for (int i = 0; i < 8; ++i)
        cact_bf[base + i] = f2bf(silu(z2[base + i]));
}

// ---------------------------------------------------------------------------
// Kernel 3 (fallback, !big): ada projections fp32 k-split (R4-proven).
// ---------------------------------------------------------------------------
__global__ __launch_bounds__(256) void ada_gemm2(const float* __restrict__ z2,
                                                 const float* __restrict__ ada_w,
                                                 const float* __restrict__ fada_w,
                                                 float* __restrict__ ada_all,
                                                 float* __restrict__ fada)
{
    const int bx = blockIdx.x, kc = blockIdx.y, tid = threadIdx.x;
    const float* W; float* Out; int ldw, colb;
    if (bx < 216) {
        const int l = bx / 18; colb = (bx % 18) * 256;
        W = ada_w + (size_t)l * HID * ADA_LD; Out = ada_all + (size_t)l * 32 * ADA_LD; ldw = ADA_LD;
    } else {
        colb = (bx - 216) * 256;
        W = fada_w; Out = fada; ldw = 1536;
    }
    const int col = colb + tid;
    const int k0 = kc * 96;
    __shared__ float cs_[32][96];
    for (int i = tid; i < 32 * 96; i += 256)
        cs_[i / 96][i % 96] = silu(z2[(size_t)(i / 96) * HID + k0 + (i % 96)]);
    __syncthreads();
    float acc[32];
    #pragma unroll
    for (int r = 0; r < 32; ++r) acc[r] = 0.f;
    #pragma unroll 2
    for (int kk = 0; kk < 96; kk += 4) {
        const float w0 = W[(size_t)(k0 + kk) * ldw + col];
        const float w1 = W[(size_t)(k0 + kk + 1) * ldw + col];
        const float w2 = W[(size_t)(k0 + kk + 2) * ldw + col];
        const float w3 = W[(size_t)(k0 + kk + 3) * ldw + col];
        #pragma unroll
        for (int r = 0; r < 32; ++r) {
            const float4 cv = *(const float4*)&cs_[r][kk];
            acc[r] += cv.x * w0 + cv.y * w1 + cv.z * w2 + cv.w * w3;
        }
    }
    #pragma unroll
    for (int r = 0; r < 32; ++r) atomicAdd(&Out[(size_t)r * ldw + col], acc[r]);
}

// ---------------------------------------------------------------------------
// Kernel 3b (big path): ada projections via bf16 MFMA, fused fp32->bf16
// weight transpose-staging. A-frags read direct from L2-hot cact_bf.
// ---------------------------------------------------------------------------
__global__ __launch_bounds__(256) void ada_mfma(const unsigned short* __restrict__ cact_bf,
                                                const float* __restrict__ ada_w,
                                                const float* __restrict__ fada_w,
                                                const float* __restrict__ ada_b,
                                                const float* __restrict__ fada_b,
                                                float* __restrict__ ada_all,
                                                float* __restrict__ fada)
{
    __shared__ unsigned short sB[2][8192];   // [buf][col 256][k 32]
    const int bx = blockIdx.x, tid = threadIdx.x;
    const float* W; const float* bias; float* Out; int ldw, colb;
    if (bx < 216) {
        const int l = bx / 18; colb = (bx % 18) * 256;
        W = ada_w + (size_t)l * HID * ADA_LD;          // [768][4608]
        bias = ada_b + (size_t)l * ADA_LD;
        Out = ada_all + (size_t)l * 32 * ADA_LD; ldw = ADA_LD;
    } else {
        colb = (bx - 216) * 256;
        W = fada_w; bias = fada_b; Out = fada; ldw = 1536;
    }
    const int lane = tid & 63, w = tid >> 6;
    const int lm = lane & 15, lg = lane >> 4;
    const int kp = tid & 15, cg = tid >> 4;            // kpair, col-group(16)
    auto stageB = [&](int buf, int kt) {
        const float* r0 = W + (size_t)(kt * 32 + 2 * kp) * ldw + colb + cg * 16;
        const float* r1 = r0 + ldw;
        unsigned int* dst = (unsigned int*)&sB[buf][0];
        #pragma unroll
        for (int c4 = 0; c4 < 4; ++c4) {
            const float4 a = *(const float4*)(r0 + c4 * 4);
            const float4 b = *(const float4*)(r1 + c4 * 4);
            const float av[4] = {a.x, a.y, a.z, a.w};
            const float bv4[4] = {b.x, b.y, b.z, b.w};
            #pragma unroll
            for (int c = 0; c < 4; ++c) {
                const int col = cg * 16 + c4 * 4 + c;
                dst[col * 16 + kp] = (unsigned int)f2bf(av[c])
                                   | ((unsigned int)f2bf(bv4[c]) << 16);
            }
        }
    };
    f32x4 acc[2][4];
    #pragma unroll
    for (int i = 0; i < 2; ++i)
        #pragma unroll
        for (int j = 0; j < 4; ++j) acc[i][j] = (f32x4){0.f, 0.f, 0.f, 0.f};
    stageB(0, 0);
    __syncthreads();
    int cur = 0;
    for (int kt = 0; kt < 24; ++kt) {
        if (kt + 1 < 24) stageB(cur ^ 1, kt + 1);
        s16x8 af[2], bfr[4];
        #pragma unroll
        for (int mi = 0; mi < 2; ++mi)
            af[mi] = *(const s16x8*)(cact_bf + (size_t)(mi * 16 + lm) * HID + kt * 32 + lg * 8);
        #pragma unroll
        for (int nj = 0; nj < 4; ++nj)
            bfr[nj] = *(const s16x8*)&sB[cur][(w * 64 + nj * 16 + lm) * 32 + lg * 8];
        #pragma unroll
        for (int mi = 0; mi < 2; ++mi)
            #pragma unroll
            for (int nj = 0; nj < 4; ++nj)
                acc[mi][nj] = __builtin_amdgcn_mfma_f32_16x16x32_bf16(af[mi], bfr[nj], acc[mi][nj], 0, 0, 0);
        __syncthreads();
        cur ^= 1;
    }
    #pragma unroll
    for (int mi = 0; mi < 2; ++mi) {
        const int row = mi * 16 + (lg << 2);
        #pragma unroll
        for (int nj = 0; nj < 4; ++nj) {
            const int col = colb + w * 64 + nj * 16 + lm;
            const float bb = bias[col];
            #pragma unroll
            for (int r = 0; r < 4; ++r)
                Out[(size_t)(row + r) * ldw + col] = acc[mi][nj][r] + bb;
        }
    }
}

// ---------------------------------------------------------------------------
// Kernel 4: patch embed + 2d sincos pos embed -> h fp32 [8192,768]
// ---------------------------------------------------------------------------
__global__ __launch_bounds__(256) void patch_embed(const float* __restrict__ x,
                                                   const float* __restrict__ pw,
                                                   const float* __restrict__ pb,
                                                   float* __restrict__ h)
{
    const int row = blockIdx.x;               // b*256 + n
    const int b = row >> 8, n = row & 255;
    const int gi = n >> 4, gj = n & 15;
    const int tid = threadIdx.x;
    __shared__ float pv[16];
    if (tid < 16) {
        const int pr = tid >> 3, pc = (tid >> 2) & 1, ci = tid & 3;
        pv[tid] = x[((size_t)(b * 32 + gi * 2 + pr) * 32 + (gj * 2 + pc)) * 4 + ci];
    }
    __syncthreads();
    #pragma unroll
    for (int cc = 0; cc < 3; ++cc) {
        const int col = cc * 256 + tid;
        float acc = pb[col];
        #pragma unroll
        for (int i = 0; i < 16; ++i) acc += pv[i] * pw[(size_t)i * HID + col];
        const int d4 = (col < 384) ? col : col - 384;   // 384 not pow2 -> no masking
        const int pos = (col < 384) ? gi : gj;
        const float kf = (float)(d4 < 192 ? d4 : d4 - 192);
        const float om = __expf(kf * (-9.210340371976184f / 192.f));
        const float a = (float)pos * om;
        acc += (d4 < 192) ? sinf(a) : cosf(a);
        h[(size_t)row * HID + col] = acc;
    }
}

// ---------------------------------------------------------------------------
// Kernel 5: weight convert fp32[K,N] -> bf16 transposed [N,K] (+ qkv bias pack)
// vectorized ushort2 transposed writes.
// ---------------------------------------------------------------------------
__global__ __launch_bounds__(256) void convert_weights(
    const float* __restrict__ q_w, const float* __restrict__ k_w,
    const float* __restrict__ v_w, const float* __restrict__ o_w,
    const float* __restrict__ fc1_w, const float* __restrict__ fc2_w,
    const float* __restrict__ q_b, const float* __restrict__ k_b,
    const float* __restrict__ v_b,
    unsigned short* __restrict__ wbase, size_t slot_stride,
    float* __restrict__ cbias, int first_layer)
{
    const int bid = blockIdx.x;
    const int l = first_layer + bid / 6913;
    const int t = bid % 6913;
    unsigned short* dst = wbase + (size_t)(bid / 6913) * slot_stride;
    const int tid = threadIdx.x;
    if (t == 6912) {
        float* cb = cbias + (size_t)l * 2304;
        for (int i = tid; i < 2304; i += 256) {
            float v;
            if (i < 768)       v = q_b[(size_t)l * 768 + i];
            else if (i < 1536) v = k_b[(size_t)l * 768 + i - 768];
            else               v = v_b[(size_t)l * 768 + i - 1536];
            cb[i] = v;
        }
        return;
    }
    const float* src; int srcN; unsigned short* d; int dLd; int tr, tc;
    if (t < 2304) {
        const int mat = t / 576, tt = t % 576; tr = tt / 24; tc = tt % 24;
        srcN = 768; dLd = 768;
        if (mat == 0)      { src = q_w + (size_t)l * 589824; d = dst; }
        else if (mat == 1) { src = k_w + (size_t)l * 589824; d = dst + 589824; }
        else if (mat == 2) { src = v_w + (size_t)l * 589824; d = dst + 1179648; }
        else               { src = o_w + (size_t)l * 589824; d = dst + 1769472; }
    } else if (t < 4608) {
        const int tt = t - 2304; tr = tt / 96; tc = tt % 96;
        src = fc1_w + (size_t)l * 2359296; srcN = 3072; dLd = 768; d = dst + 2359296;
    } else {
        const int tt = t - 4608; tr = tt / 24; tc = tt % 24;
        src = fc2_w + (size_t)l * 2359296; srcN = 768; dLd = 3072; d = dst + 4718592;
    }
    __shared__ float lt[32][33];
    const int tx = tid & 31, ty = tid >> 5;
    const int r0 = tr * 32, c0 = tc * 32;
    #pragma unroll
    for (int i = 0; i < 4; ++i)
        lt[ty + i * 8][tx] = src[(size_t)(r0 + ty + i * 8) * srcN + c0 + tx];
    __syncthreads();
    const int q = tid & 15;          // row-pair index (rows 2q, 2q+1)
    const int cw = tid >> 4;         // 16 cols per pass
    #pragma unroll
    for (int i = 0; i < 2; ++i) {
        const int cc = cw + i * 16;
        const unsigned int pk = (unsigned int)f2bf(lt[2 * q][cc])
                              | ((unsigned int)f2bf(lt[2 * q + 1][cc]) << 16);
        *(unsigned int*)&d[(size_t)(c0 + cc) * dLd + r0 + 2 * q] = pk;
    }
}

// ---------------------------------------------------------------------------
// Kernel 6: LayerNorm (no affine) + adaLN modulate -> bf16.
// grid 2048, 4 rows/block, 192 thr, float4 io.
// ---------------------------------------------------------------------------
__global__ __launch_bounds__(192) void ln_mod(const float* __restrict__ hbuf,
                                              const float* __restrict__ mod,
                                              int sh_off, int sc_off, int mld,
                                              unsigned short* __restrict__ xout)
{
    const int tid = threadIdx.x;
    __shared__ float sb[3], ssb[3];
    #pragma unroll
    for (int rr = 0; rr < 4; ++rr) {
        const int row = blockIdx.x * 4 + rr;
        const float4 xv = *(const float4*)&hbuf[(size_t)row * HID + tid * 4];
        float s = (xv.x + xv.y) + (xv.z + xv.w);
        float ss = (xv.x * xv.x + xv.y * xv.y) + (xv.z * xv.z + xv.w * xv.w);
        #pragma unroll
        for (int d = 1; d < 64; d <<= 1) { s += __shfl_xor(s, d); ss += __shfl_xor(ss, d); }
        if ((tid & 63) == 0) { sb[tid >> 6] = s; ssb[tid >> 6] = ss; }
        __syncthreads();
        s = sb[0] + sb[1] + sb[2];
        ss = ssb[0] + ssb[1] + ssb[2];
        const float mean = s * (1.f / 768.f);
        const float var = ss * (1.f / 768.f) - mean * mean;
        const float rs = rsqrtf(var + 1e-5f);
        const int b = row >> 8;
        const float* mrow = mod + (size_t)b * mld;
        const float4 sc = *(const float4*)&mrow[sc_off + tid * 4];
        const float4 sh = *(const float4*)&mrow[sh_off + tid * 4];
        ushort4 o;
        o.x = f2bf((xv.x - mean) * rs * (1.f + sc.x) + sh.x);
        o.y = f2bf((xv.y - mean) * rs * (1.f + sc.y) + sh.y);
        o.z = f2bf((xv.z - mean) * rs * (1.f + sc.z) + sh.z);
        o.w = f2bf((xv.w - mean) * rs * (1.f + sc.w) + sh.w);
        *(ushort4*)&xout[(size_t)row * HID + tid * 4] = o;
        __syncthreads();   // protect sb/ssb before next row's write
    }
}

// ---------------------------------------------------------------------------
// Kernel 7: bf16 MFMA GEMM, C = A[M,K] @ B[K,N] (+epilogues), B given as [N,K].
// Tile 128M x BN, BK=32, 4 waves (2x2), 16x16x32 MFMA.
// global_load_lds width-16 staging + LDS double-buffer, 1 barrier/K-step.
// T1: bijective XCD swizzle (grids all %8==0).
// RT>1: each block processes RT row-tiles (rowbase + rt*gridDim.y*128),
// reusing the staging pipeline across the seam (last K-iter of tile rt
// issues tile rt+1's kt=0 loads; epilogue overlaps them). acc reused.
// Fixes fc1's 1536-block over-subscription (capacity 1280 -> 256-block tail).
// EPI 0: bf16(acc+bias) ; EPI 1: bf16(gelu_exact(acc+bias)) ;
// EPI 2: h += gate[b][col]*(acc+bias)
// ---------------------------------------------------------------------------
template<int EPI, int BN, int RT>
__global__ __launch_bounds__(256) void gemm_bt(const unsigned short* __restrict__ A,
                                               const unsigned short* __restrict__ Bt,
                                               const float* __restrict__ bias,
                                               void* __restrict__ outp,
                                               const float* __restrict__ gate,
                                               int K, int ldo)
{
    constexpr int BELEMS = BN * 32;
    constexpr int NJ = BN / 32;
    __shared__ unsigned short sAB[2][4096 + BELEMS];
    const int tid = threadIdx.x;
    const int lane = tid & 63;
    const int w = tid >> 6;
    const int wm = w >> 1, wn = w & 1;
    const int nwg = gridDim.x * gridDim.y;
    int bidl = blockIdx.y * gridDim.x + blockIdx.x;
    bidl = (bidl & 7) * (nwg >> 3) + (bidl >> 3);
    const int bx = bidl % gridDim.x, by = bidl / gridDim.x;
    const int rowbase = by << 7;
    const int colbase = bx * BN;
    const size_t aStep = (size_t)(gridDim.y << 7) * K;   // row-tile stride
    const size_t a0 = (size_t)(rowbase +      (tid >> 2)) * K + (tid & 3) * 8;
    const size_t a1 = (size_t)(rowbase + 64 + (tid >> 2)) * K + (tid & 3) * 8;
    const size_t b0 = (size_t)(colbase +      (tid >> 2)) * K + (tid & 3) * 8;
    size_t b1 = 0;
    if constexpr (BN == 128)
        b1 = (size_t)(colbase + 64 + (tid >> 2)) * K + (tid & 3) * 8;
    const int ldsw = w * 512;
    f32x4 acc[4][NJ];
    #pragma unroll
    for (int i = 0; i < 4; ++i)
        #pragma unroll
        for (int j = 0; j < NJ; ++j) acc[i][j] = (f32x4){0.f, 0.f, 0.f, 0.f};
    const int nk = K >> 5;
    const int lm = lane & 15, lg = lane >> 4;
    auto stage = [&](unsigned short* base, int kt, int rt_) {
        const size_t ash = (size_t)rt_ * aStep + ((size_t)kt << 5);
        const size_t bsh = (size_t)kt << 5;
        gload16(A + a0 + ash,  base + ldsw);
        gload16(A + a1 + ash,  base + 2048 + ldsw);
        gload16(Bt + b0 + bsh, base + 4096 + ldsw);
        if constexpr (BN == 128) gload16(Bt + b1 + bsh, base + 6144 + ldsw);
    };
    stage(&sAB[0][0], 0, 0);
    __syncthreads();
    int cur = 0;
    #pragma unroll
    for (int rt = 0; rt < RT; ++rt) {
        for (int kt = 0; kt < nk; ++kt) {
            if (kt + 1 < nk)          stage(&sAB[cur ^ 1][0], kt + 1, rt);
            else if (rt + 1 < RT)     stage(&sAB[cur ^ 1][0], 0, rt + 1);
            const unsigned short* sAc = &sAB[cur][0];
            const unsigned short* sBc = &sAB[cur][4096];
            s16x8 af[4], bfr[NJ];
            #pragma unroll
            for (int mi = 0; mi < 4; ++mi)
                af[mi] = *(const s16x8*)&sAc[(wm * 64 + mi * 16 + lm) * 32 + lg * 8];
            #pragma unroll
            for (int nj = 0; nj < NJ; ++nj)
                bfr[nj] = *(const s16x8*)&sBc[(wn * (16 * NJ) + nj * 16 + lm) * 32 + lg * 8];
            #pragma unroll
            for (int mi = 0; mi < 4; ++mi)
                #pragma unroll
                for (int nj = 0; nj < NJ; ++nj)
                    acc[mi][nj] = __builtin_amdgcn_mfma_f32_16x16x32_bf16(af[mi], bfr[nj], acc[mi][nj], 0, 0, 0);
            __syncthreads();   // drains this iter's global_load_lds
            cur ^= 1;
        }
        // epilogue for this row-tile (in-flight loads for rt+1 keep moving)
        const int rowb = rowbase + rt * (gridDim.y << 7);
        float bv[NJ], gv[NJ];
        #pragma unroll
        for (int nj = 0; nj < NJ; ++nj) {
            const int col = colbase + wn * (16 * NJ) + nj * 16 + lm;
            bv[nj] = bias[col];
            if constexpr (EPI == 2) gv[nj] = gate[(size_t)(rowb >> 8) * ADA_LD + col];
        }
        #pragma unroll
        for (int mi = 0; mi < 4; ++mi) {
            const int row = rowb + wm * 64 + mi * 16 + (lg << 2);
            #pragma unroll
            for (int nj = 0; nj < NJ; ++nj) {
                const int col = colbase + wn * (16 * NJ) + nj * 16 + lm;
                #pragma unroll
                for (int r = 0; r < 4; ++r) {
                    const float v = acc[mi][nj][r] + bv[nj];
                    if constexpr (EPI == 0) {
                        ((unsigned short*)outp)[(size_t)(row + r) * ldo + col] = f2bf(v);
                    } else if constexpr (EPI == 1) {
                        const float g = 0.5f * v * (1.f + erff(v * 0.70710678118654752f));
                        ((unsigned short*)outp)[(size_t)(row + r) * ldo + col] = f2bf(g);
                    } else {
                        float* O = (float*)outp;
                        const size_t idx = (size_t)(row + r) * ldo + col;
                        O[idx] = O[idx] + gv[nj] * v;
                    }
                }
            }
        }
        if (rt + 1 < RT) {
            #pragma unroll
            for (int i = 0; i < 4; ++i)
                #pragma unroll
                for (int j = 0; j < NJ; ++j) acc[i][j] = (f32x4){0.f, 0.f, 0.f, 0.f};
        }
    }
}

// ---------------------------------------------------------------------------
// Kernel 8: fused attention (4 waves x 32 q-rows, T5 setprio).
// ---------------------------------------------------------------------------
__global__ __launch_bounds__(256) void attn_fused(const unsigned short* __restrict__ qkv,
                                                  unsigned short* __restrict__ yv)
{
    __shared__ unsigned short Vt[64][264];
    __shared__ unsigned short Psm[4][32 * 72];
    __shared__ float Ssc[4][32];
    const int bid = blockIdx.x;
    const int b = bid / 24, rem = bid % 24, h = rem >> 1, half = rem & 1;
    const int tid = threadIdx.x, w = tid >> 6, lane = tid & 63;
    {
        const int dhg = tid & 7, tk = tid >> 3;
        #pragma unroll
        for (int g = 0; g < 8; ++g) {
            const int tok = tk + g * 32;
            s16x8 vv = *(const s16x8*)(qkv + (size_t)(b * 256 + tok) * 2304 + 1536 + h * 64 + dhg * 8);
            #pragma unroll
            for (int j = 0; j < 8; ++j) Vt[dhg * 8 + j][tok] = (unsigned short)vv[j];
        }
    }
    __syncthreads();
    const int q0 = half * 128 + w * 32;
    const int lm = lane & 15, lg = lane >> 4;
    const unsigned short* Qb = qkv + (size_t)(b * 256 + q0) * 2304 + h * 64;
    s16x8 qf[2][2];
    #pragma unroll
    for (int ni = 0; ni < 2; ++ni)
        #pragma unroll
        for (int kk = 0; kk < 2; ++kk)
            qf[ni][kk] = *(const s16x8*)(Qb + (size_t)(ni * 16 + lm) * 2304 + kk * 32 + lg * 8);
    f32x4 o_[2][4];
    #pragma unroll
    for (int i = 0; i < 2; ++i)
        #pragma unroll
        for (int j = 0; j < 4; ++j) o_[i][j] = (f32x4){0.f, 0.f, 0.f, 0.f};
    float m_[2], l_[2];
    #pragma unroll
    for (int i = 0; i < 2; ++i) { m_[i] = -1e30f; l_[i] = 0.f; }
    const float s3 = 0.57735026918962576f;   // 1/sqrt(3)
    for (int c = 0; c < 4; ++c) {
        f32x4 st[4][2];
        #pragma unroll
        for (int i = 0; i < 4; ++i)
            #pragma unroll
            for (int j = 0; j < 2; ++j) st[i][j] = (f32x4){0.f, 0.f, 0.f, 0.f};
        const unsigned short* Kb = qkv + (size_t)(b * 256 + c * 64) * 2304 + 768 + h * 64;
        __builtin_amdgcn_s_setprio(1);
        #pragma unroll
        for (int kk = 0; kk < 2; ++kk)
            #pragma unroll
            for (int mi = 0; mi < 4; ++mi) {
                const s16x8 kf = *(const s16x8*)(Kb + (size_t)(mi * 16 + lm) * 2304 + kk * 32 + lg * 8);
                #pragma unroll
                for (int ni = 0; ni < 2; ++ni)
                    st[mi][ni] = __builtin_amdgcn_mfma_f32_16x16x32_bf16(kf, qf[ni][kk], st[mi][ni], 0, 0, 0);
            }
        __builtin_amdgcn_s_setprio(0);
        #pragma unroll
        for (int ni = 0; ni < 2; ++ni) {
            float cm = -1e30f;
            #pragma unroll
            for (int mi = 0; mi < 4; ++mi)
                #pragma unroll
                for (int r = 0; r < 4; ++r) cm = fmaxf(cm, st[mi][ni][r]);
            cm = fmaxf(cm, __shfl_xor(cm, 16));
            cm = fmaxf(cm, __shfl_xor(cm, 32));
            cm *= s3;
            const float mn = fmaxf(m_[ni], cm);
            const float corr = __expf(m_[ni] - mn);
            float cs = 0.f;
            #pragma unroll
            for (int mi = 0; mi < 4; ++mi) {
                float p0 = __expf(st[mi][ni][0] * s3 - mn);
                float p1 = __expf(st[mi][ni][1] * s3 - mn);
                float p2 = __expf(st[mi][ni][2] * s3 - mn);
                float p3 = __expf(st[mi][ni][3] * s3 - mn);
                cs += (p0 + p1) + (p2 + p3);
                uint2 pk;
                pk.x = (unsigned int)f2bf(p0) | ((unsigned int)f2bf(p1) << 16);
                pk.y = (unsigned int)f2bf(p2) | ((unsigned int)f2bf(p3) << 16);
                *(uint2*)&Psm[w][(ni * 16 + lm) * 72 + mi * 16 + lg * 4] = pk;
            }
            cs += __shfl_xor(cs, 16);
            cs += __shfl_xor(cs, 32);
            l_[ni] = l_[ni] * corr + cs;
            m_[ni] = mn;
            if (lane < 16) Ssc[w][ni * 16 + lane] = corr;
        }
        asm volatile("" ::: "memory");
        #pragma unroll
        for (int qi = 0; qi < 2; ++qi) {
            float fr[4];
            #pragma unroll
            for (int r = 0; r < 4; ++r) fr[r] = Ssc[w][qi * 16 + lg * 4 + r];
            #pragma unroll
            for (int di = 0; di < 4; ++di)
                #pragma unroll
                for (int r = 0; r < 4; ++r) o_[qi][di][r] *= fr[r];
        }
        __builtin_amdgcn_s_setprio(1);
        #pragma unroll
        for (int kk = 0; kk < 2; ++kk)
            #pragma unroll
            for (int qi = 0; qi < 2; ++qi) {
                const s16x8 pa = *(const s16x8*)&Psm[w][(qi * 16 + lm) * 72 + kk * 32 + lg * 8];
                #pragma unroll
                for (int di = 0; di < 4; ++di) {
                    const s16x8 vb = *(const s16x8*)&Vt[di * 16 + lm][c * 64 + kk * 32 + lg * 8];
                    o_[qi][di] = __builtin_amdgcn_mfma_f32_16x16x32_bf16(pa, vb, o_[qi][di], 0, 0, 0);
                }
            }
        __builtin_amdgcn_s_setprio(0);
    }
    asm volatile("" ::: "memory");
    if (lane < 16) {
        #pragma unroll
        for (int ni = 0; ni < 2; ++ni) Ssc[w][ni * 16 + lane] = 1.f / l_[ni];
    }
    asm volatile("" ::: "memory");
    #pragma unroll
    for (int qi = 0; qi < 2; ++qi) {
        float fr[4];
        #pragma unroll
        for (int r = 0; r < 4; ++r) fr[r] = Ssc[w][qi * 16 + lg * 4 + r];
        #pragma unroll
        for (int di = 0; di < 4; ++di)
            #pragma unroll
            for (int r = 0; r < 4; ++r) {
                const float val = o_[qi][di][r] * fr[r];
                yv[(size_t)(b * 256 + q0 + qi * 16 + lg * 4 + r) * HID + h * 64 + di * 16 + lm] = f2bf(val);
            }
    }
}

// ---------------------------------------------------------------------------
// Kernel 9: final projection  out[8192,16] = xn @ fin_w[768,16] + fin_b
// ---------------------------------------------------------------------------
__global__ __launch_bounds__(256) void fin_gemm(const unsigned short* __restrict__ xn,
                                                const float* __restrict__ w,
                                                const float* __restrict__ bias,
                                                float* __restrict__ out)
{
    __shared__ unsigned short xs[16 * 768];
    const int rb = blockIdx.x * 16, tid = threadIdx.x;
    #pragma unroll
    for (int i = 0; i < 6; ++i) {
        const int v = tid + i * 256;
        const int row = v / 96, koff = (v % 96) * 8;
        *(s16x8*)&xs[v * 8] = *(const s16x8*)(xn + (size_t)(rb + row) * HID + koff);
    }
    __syncthreads();
    const int r = tid >> 4, o = tid & 15;
    float acc = bias[o];
    #pragma unroll 8
    for (int k = 0; k < 768; ++k) acc += bf2f(xs[r * 768 + k]) * w[(size_t)k * 16 + o];
    out[(size_t)(rb + r) * 16 + o] = acc;
}

// ---------------------------------------------------------------------------
// Host launcher
// ---------------------------------------------------------------------------
extern "C" void kernel_launch(void* const* d_in, const int* in_sizes, int n_in,
                              void* d_out, int out_size, void* d_ws, size_t ws_size,
                              hipStream_t stream)
{
    const float* x        = (const float*)d_in[0];
    const float* t        = (const float*)d_in[1];
    const int*   y        = (const int*)d_in[2];
    const float* patch_w  = (const float*)d_in[3];
    const float* patch_b  = (const float*)d_in[4];
    const float* t_w1     = (const float*)d_in[5];
    const float* t_b1     = (const float*)d_in[6];
    const float* t_w2     = (const float*)d_in[7];
    const float* t_b2     = (const float*)d_in[8];
    const float* label_e  = (const float*)d_in[9];
    const float* ada_w    = (const float*)d_in[10];
    const float* ada_b    = (const float*)d_in[11];
    const float* q_w      = (const float*)d_in[12];
    const float* q_b      = (const float*)d_in[13];
    const float* k_w      = (const float*)d_in[14];
    const float* k_b      = (const float*)d_in[15];
    const float* v_w      = (const float*)d_in[16];
    const float* v_b      = (const float*)d_in[17];
    const float* o_w      = (const float*)d_in[18];
    const float* o_b      = (const float*)d_in[19];
    const float* fc1_w    = (const float*)d_in[20];
    const float* fc1_b    = (const float*)d_in[21];
    const float* fc2_w    = (const float*)d_in[22];
    const float* fc2_b    = (const float*)d_in[23];
    const float* fada_w   = (const float*)d_in[24];
    const float* fada_b   = (const float*)d_in[25];
    const float* fin_w    = (const float*)d_in[26];
    const float* fin_b    = (const float*)d_in[27];

    char* ws = (char*)d_ws;
    size_t off = 0;
    auto alloc = [&](size_t bytes) { size_t o = off; off = (off + bytes + 255) & ~(size_t)255; return o; };
    const size_t OFF_H     = alloc((size_t)ROWS * HID * 4);
    const size_t OFF_XN    = alloc((size_t)ROWS * HID * 2);
    const size_t OFF_QKV   = alloc((size_t)ROWS * 2304 * 2);
    const size_t OFF_YV    = alloc((size_t)ROWS * HID * 2);
    const size_t OFF_MLP   = alloc((size_t)ROWS * MLPD * 2);
    const size_t OFF_ADA   = alloc((size_t)12 * 32 * ADA_LD * 4);
    const size_t OFF_FADA  = alloc((size_t)32 * 1536 * 4);
    const size_t OFF_Z2    = alloc((size_t)32 * HID * 4);
    const size_t OFF_Z1    = alloc((size_t)32 * HID * 4);
    const size_t OFF_CB    = alloc((size_t)12 * 2304 * 4);
    const size_t OFF_CBF   = alloc((size_t)32 * HID * 2);
    const size_t OFF_W     = off;
    const size_t WSLOT_ELEMS = 7077888;  // per-layer bf16 weight elems
    const bool big = (ws_size >= OFF_W + (size_t)12 * WSLOT_ELEMS * 2);

    float*          h     = (float*)(ws + OFF_H);
    unsigned short* xn    = (unsigned short*)(ws + OFF_XN);
    unsigned short* qkv   = (unsigned short*)(ws + OFF_QKV);
    unsigned short* yv    = (unsigned short*)(ws + OFF_YV);
    unsigned short* mlp   = (unsigned short*)(ws + OFF_MLP);
    float*          adaA  = (float*)(ws + OFF_ADA);
    float*          fada  = (float*)(ws + OFF_FADA);
    float*          z2    = (float*)(ws + OFF_Z2);
    float*          z1    = (float*)(ws + OFF_Z1);
    float*          cbias = (float*)(ws + OFF_CB);
    unsigned short* cactb = (unsigned short*)(ws + OFF_CBF);
    unsigned short* wsW   = (unsigned short*)(ws + OFF_W);

    // startup: conditioning chain, ada, patch, weight convert
    if (big) {
        ada_init<<<3, 256, 0, stream>>>(ada_b, fada_b, t_b1, t_b2, label_e, y,
                                        adaA, fada, z1, z2, 222);
    } else {
        ada_init<<<225, 256, 0, stream>>>(ada_b, fada_b, t_b1, t_b2, label_e, y,
                                          adaA, fada, z1, z2, 0);
    }
    temb1_k<<<dim3(32, 3, 2), 256, 0, stream>>>(t, t_w1, z1);
    temb2_k<<<dim3(32, 3, 4), 256, 0, stream>>>(z1, t_w2, z2);
    if (big) {
        csilu_k<<<12, 256, 0, stream>>>(z2, cactb);
        ada_mfma<<<222, 256, 0, stream>>>(cactb, ada_w, fada_w, ada_b, fada_b, adaA, fada);
        convert_weights<<<6913 * 12, 256, 0, stream>>>(q_w, k_w, v_w, o_w, fc1_w, fc2_w,
                                                       q_b, k_b, v_b, wsW, WSLOT_ELEMS, cbias, 0);
    } else {
        ada_gemm2<<<dim3(222, 8), 256, 0, stream>>>(z2, ada_w, fada_w, adaA, fada);
    }
    patch_embed<<<8192, 256, 0, stream>>>(x, patch_w, patch_b, h);

    for (int l = 0; l < 12; ++l) {
        unsigned short* wslot = wsW + (big ? (size_t)l * WSLOT_ELEMS : 0);
        if (!big) {
            convert_weights<<<6913, 256, 0, stream>>>(q_w, k_w, v_w, o_w, fc1_w, fc2_w,
                                                      q_b, k_b, v_b, wslot, 0, cbias, l);
        }
        unsigned short* qkvT = wslot;
        unsigned short* oT   = wslot + 1769472;
        unsigned short* f1T  = wslot + 2359296;
        unsigned short* f2T  = wslot + 4718592;
        float* ada_l  = adaA + (size_t)l * 32 * ADA_LD;
        float* cb_l   = cbias + (size_t)l * 2304;

        ln_mod<<<2048, 192, 0, stream>>>(h, ada_l, 0, 768, ADA_LD, xn);
        gemm_bt<0, 128, 1><<<dim3(18, 64), 256, 0, stream>>>(xn, qkvT, cb_l, qkv, nullptr, 768, 2304);
        attn_fused<<<768, 256, 0, stream>>>(qkv, yv);
        gemm_bt<2, 64, 1><<<dim3(12, 64), 256, 0, stream>>>(yv, oT, o_b + (size_t)l * 768, h,
                                                            ada_l + 1536, 768, 768);
        ln_mod<<<2048, 192, 0, stream>>>(h, ada_l, 2304, 3072, ADA_LD, xn);
        // fc1: RT=2 row-tiles -> 768 blocks (all resident; kills the 256-block tail)
        gemm_bt<1, 128, 2><<<dim3(24, 32), 256, 0, stream>>>(xn, f1T, fc1_b + (size_t)l * 3072, mlp,
                                                             nullptr, 768, 3072);
        gemm_bt<2, 64, 1><<<dim3(12, 64), 256, 0, stream>>>(mlp, f2T, fc2_b + (size_t)l * 768, h,
                                                            ada_l + 3840, 3072, 768);
    }

    // final layer
    ln_mod<<<2048, 192, 0, stream>>>(h, fada, 0, 768, 1536, xn);
    fin_gemm<<<512, 256, 0, stream>>>(xn, fin_w, fin_b, (float*)d_out);
}

// Round 14
// 3215.709 us; speedup vs baseline: 1.0362x; 1.0362x over previous
//
#include <hip/hip_runtime.h>
#include <hip/hip_bf16.h>

// ---------------------------------------------------------------------------
// DiT forward, bf16-MFMA implementation.
// B=32, IMG=32, CIN=4, PATCH=2, HIDDEN=768, DEPTH=12, HEADS=12 (dh=64),
// MLP=3072, N=256 tokens, rows = B*N = 8192.
// ---------------------------------------------------------------------------

typedef short  s16x8 __attribute__((ext_vector_type(8)));
typedef float  f32x4 __attribute__((ext_vector_type(4)));

__device__ __forceinline__ float bf2f(unsigned short u) {
    union { unsigned int i; float f; } v; v.i = ((unsigned int)u) << 16; return v.f;
}
__device__ __forceinline__ unsigned short f2bf(float f) {
    union { float f; unsigned int i; } v; v.f = f;
    unsigned int r = (v.i + 0x7FFFu + ((v.i >> 16) & 1u)) >> 16;
    return (unsigned short)r;
}
__device__ __forceinline__ float silu(float v) { return v / (1.f + __expf(-v)); }

// async global->LDS, 16B per lane. Global addr is PER-LANE; LDS dest is
// wave-uniform base, HW writes lane i at base + i*16B. [m97/m104]
__device__ __forceinline__ void gload16(const void* gptr, void* lptr) {
    __builtin_amdgcn_global_load_lds(
        (const __attribute__((address_space(1))) unsigned int*)gptr,
        (__attribute__((address_space(3))) unsigned int*)lptr,
        16, 0, 0);
}

#define ROWS 8192
#define HID  768
#define MLPD 3072
#define ADA_LD 4608

// ---------------------------------------------------------------------------
// Kernel 0: init targets. bid0=222 (grid 3): z1/z2 only (big path).
// bid0=0 (grid 225): also bias-init ada/fada for the atomic fallback path.
// ---------------------------------------------------------------------------
__global__ __launch_bounds__(256) void ada_init(const float* __restrict__ ada_b,
                                                const float* __restrict__ fada_b,
                                                const float* __restrict__ t_b1,
                                                const float* __restrict__ t_b2,
                                                const float* __restrict__ lemb,
                                                const int* __restrict__ y,
                                                float* __restrict__ ada_all,
                                                float* __restrict__ fada,
                                                float* __restrict__ z1,
                                                float* __restrict__ z2,
                                                int bid0)
{
    const int bid = blockIdx.x + bid0, tid = threadIdx.x;
    if (bid >= 222) {
        const int col = (bid - 222) * 256 + tid;
        const float b1v = t_b1[col], b2v = t_b2[col];
        for (int r = 0; r < 32; ++r) {
            z1[(size_t)r * HID + col] = b1v;
            z2[(size_t)r * HID + col] = b2v + lemb[(size_t)y[r] * HID + col];
        }
        return;
    }
    const float* Bv; float* Out; int ldw, colb;
    if (bid < 216) {
        const int l = bid / 18; colb = (bid % 18) * 256;
        Bv = ada_b + (size_t)l * ADA_LD; Out = ada_all + (size_t)l * 32 * ADA_LD; ldw = ADA_LD;
    } else {
        colb = (bid - 216) * 256;
        Bv = fada_b; Out = fada; ldw = 1536;
    }
    const int col = colb + tid;
    const float bb = Bv[col];
    #pragma unroll
    for (int r = 0; r < 32; ++r) Out[(size_t)r * ldw + col] = bb;
}

// ---------------------------------------------------------------------------
// Kernel 1: timestep embedding stage 1 (k-split), grid (32, 3, 2)
// ---------------------------------------------------------------------------
__global__ __launch_bounds__(256) void temb1_k(const float* __restrict__ t,
                                               const float* __restrict__ w1,
                                               float* __restrict__ z1)
{
    __shared__ float tin[128];
    const int b = blockIdx.x, cc = blockIdx.y, kc = blockIdx.z, tid = threadIdx.x;
    const int k0 = kc * 128;
    if (tid < 128) {
        const int k = k0 + tid, j = k & 127;
        const float fr = __expf((float)j * (-9.210340371976184f / 128.f));
        const float a = t[b] * fr;
        tin[tid] = (k < 128) ? cosf(a) : sinf(a);
    }
    __syncthreads();
    const int col = cc * 256 + tid;
    float acc = 0.f;
    #pragma unroll 8
    for (int kk = 0; kk < 128; ++kk) acc += tin[kk] * w1[(size_t)(k0 + kk) * HID + col];
    atomicAdd(&z1[(size_t)b * HID + col], acc);
}

// ---------------------------------------------------------------------------
// Kernel 2: stage 2 (k-split), grid (32, 3, 4)
// ---------------------------------------------------------------------------
__global__ __launch_bounds__(256) void temb2_k(const float* __restrict__ z1,
                                               const float* __restrict__ w2,
                                               float* __restrict__ z2)
{
    __shared__ float tin[192];
    const int b = blockIdx.x, cc = blockIdx.y, kc = blockIdx.z, tid = threadIdx.x;
    const int k0 = kc * 192;
    if (tid < 192) tin[tid] = silu(z1[(size_t)b * HID + k0 + tid]);
    __syncthreads();
    const int col = cc * 256 + tid;
    float acc = 0.f;
    #pragma unroll 8
    for (int kk = 0; kk < 192; ++kk) acc += tin[kk] * w2[(size_t)(k0 + kk) * HID + col];
    atomicAdd(&z2[(size_t)b * HID + col], acc);
}

// ---------------------------------------------------------------------------
// Kernel 2b: cact_bf = bf16(silu(z2))  [32][768]
// ---------------------------------------------------------------------------
__global__ __launch_bounds__(256) void csilu_k(const float* __restrict__ z2,
                                               unsigned short* __restrict__ cact_bf)
{
    const int base = (blockIdx.x * 256 + threadIdx.x) * 8;
    #pragma unroll
    for (int i = 0; i < 8; ++i)
        cact_bf[base + i] = f2bf(silu(z2[base + i]));
}

// ---------------------------------------------------------------------------
// Kernel 3 (fallback, !big): ada projections fp32 k-split (R4-proven).
// ---------------------------------------------------------------------------
__global__ __launch_bounds__(256) void ada_gemm2(const float* __restrict__ z2,
                                                 const float* __restrict__ ada_w,
                                                 const float* __restrict__ fada_w,
                                                 float* __restrict__ ada_all,
                                                 float* __restrict__ fada)
{
    const int bx = blockIdx.x, kc = blockIdx.y, tid = threadIdx.x;
    const float* W; float* Out; int ldw, colb;
    if (bx < 216) {
        const int l = bx / 18; colb = (bx % 18) * 256;
        W = ada_w + (size_t)l * HID * ADA_LD; Out = ada_all + (size_t)l * 32 * ADA_LD; ldw = ADA_LD;
    } else {
        colb = (bx - 216) * 256;
        W = fada_w; Out = fada; ldw = 1536;
    }
    const int col = colb + tid;
    const int k0 = kc * 96;
    __shared__ float cs_[32][96];
    for (int i = tid; i < 32 * 96; i += 256)
        cs_[i / 96][i % 96] = silu(z2[(size_t)(i / 96) * HID + k0 + (i % 96)]);
    __syncthreads();
    float acc[32];
    #pragma unroll
    for (int r = 0; r < 32; ++r) acc[r] = 0.f;
    #pragma unroll 2
    for (int kk = 0; kk < 96; kk += 4) {
        const float w0 = W[(size_t)(k0 + kk) * ldw + col];
        const float w1 = W[(size_t)(k0 + kk + 1) * ldw + col];
        const float w2 = W[(size_t)(k0 + kk + 2) * ldw + col];
        const float w3 = W[(size_t)(k0 + kk + 3) * ldw + col];
        #pragma unroll
        for (int r = 0; r < 32; ++r) {
            const float4 cv = *(const float4*)&cs_[r][kk];
            acc[r] += cv.x * w0 + cv.y * w1 + cv.z * w2 + cv.w * w3;
        }
    }
    #pragma unroll
    for (int r = 0; r < 32; ++r) atomicAdd(&Out[(size_t)r * ldw + col], acc[r]);
}

// ---------------------------------------------------------------------------
// Kernel 3b (big path): ada projections via bf16 MFMA, fused fp32->bf16
// weight transpose-staging. A-frags read direct from L2-hot cact_bf.
// ---------------------------------------------------------------------------
__global__ __launch_bounds__(256) void ada_mfma(const unsigned short* __restrict__ cact_bf,
                                                const float* __restrict__ ada_w,
                                                const float* __restrict__ fada_w,
                                                const float* __restrict__ ada_b,
                                                const float* __restrict__ fada_b,
                                                float* __restrict__ ada_all,
                                                float* __restrict__ fada)
{
    __shared__ unsigned short sB[2][8192];   // [buf][col 256][k 32]
    const int bx = blockIdx.x, tid = threadIdx.x;
    const float* W; const float* bias; float* Out; int ldw, colb;
    if (bx < 216) {
        const int l = bx / 18; colb = (bx % 18) * 256;
        W = ada_w + (size_t)l * HID * ADA_LD;          // [768][4608]
        bias = ada_b + (size_t)l * ADA_LD;
        Out = ada_all + (size_t)l * 32 * ADA_LD; ldw = ADA_LD;
    } else {
        colb = (bx - 216) * 256;
        W = fada_w; bias = fada_b; Out = fada; ldw = 1536;
    }
    const int lane = tid & 63, w = tid >> 6;
    const int lm = lane & 15, lg = lane >> 4;
    const int kp = tid & 15, cg = tid >> 4;            // kpair, col-group(16)
    auto stageB = [&](int buf, int kt) {
        const float* r0 = W + (size_t)(kt * 32 + 2 * kp) * ldw + colb + cg * 16;
        const float* r1 = r0 + ldw;
        unsigned int* dst = (unsigned int*)&sB[buf][0];
        #pragma unroll
        for (int c4 = 0; c4 < 4; ++c4) {
            const float4 a = *(const float4*)(r0 + c4 * 4);
            const float4 b = *(const float4*)(r1 + c4 * 4);
            const float av[4] = {a.x, a.y, a.z, a.w};
            const float bv4[4] = {b.x, b.y, b.z, b.w};
            #pragma unroll
            for (int c = 0; c < 4; ++c) {
                const int col = cg * 16 + c4 * 4 + c;
                dst[col * 16 + kp] = (unsigned int)f2bf(av[c])
                                   | ((unsigned int)f2bf(bv4[c]) << 16);
            }
        }
    };
    f32x4 acc[2][4];
    #pragma unroll
    for (int i = 0; i < 2; ++i)
        #pragma unroll
        for (int j = 0; j < 4; ++j) acc[i][j] = (f32x4){0.f, 0.f, 0.f, 0.f};
    stageB(0, 0);
    __syncthreads();
    int cur = 0;
    for (int kt = 0; kt < 24; ++kt) {
        if (kt + 1 < 24) stageB(cur ^ 1, kt + 1);
        s16x8 af[2], bfr[4];
        #pragma unroll
        for (int mi = 0; mi < 2; ++mi)
            af[mi] = *(const s16x8*)(cact_bf + (size_t)(mi * 16 + lm) * HID + kt * 32 + lg * 8);
        #pragma unroll
        for (int nj = 0; nj < 4; ++nj)
            bfr[nj] = *(const s16x8*)&sB[cur][(w * 64 + nj * 16 + lm) * 32 + lg * 8];
        #pragma unroll
        for (int mi = 0; mi < 2; ++mi)
            #pragma unroll
            for (int nj = 0; nj < 4; ++nj)
                acc[mi][nj] = __builtin_amdgcn_mfma_f32_16x16x32_bf16(af[mi], bfr[nj], acc[mi][nj], 0, 0, 0);
        __syncthreads();
        cur ^= 1;
    }
    #pragma unroll
    for (int mi = 0; mi < 2; ++mi) {
        const int row = mi * 16 + (lg << 2);
        #pragma unroll
        for (int nj = 0; nj < 4; ++nj) {
            const int col = colb + w * 64 + nj * 16 + lm;
            const float bb = bias[col];
            #pragma unroll
            for (int r = 0; r < 4; ++r)
                Out[(size_t)(row + r) * ldw + col] = acc[mi][nj][r] + bb;
        }
    }
}

// ---------------------------------------------------------------------------
// Kernel 4: patch embed + 2d sincos pos embed -> h fp32 [8192,768]
// ---------------------------------------------------------------------------
__global__ __launch_bounds__(256) void patch_embed(const float* __restrict__ x,
                                                   const float* __restrict__ pw,
                                                   const float* __restrict__ pb,
                                                   float* __restrict__ h)
{
    const int row = blockIdx.x;               // b*256 + n
    const int b = row >> 8, n = row & 255;
    const int gi = n >> 4, gj = n & 15;
    const int tid = threadIdx.x;
    __shared__ float pv[16];
    if (tid < 16) {
        const int pr = tid >> 3, pc = (tid >> 2) & 1, ci = tid & 3;
        pv[tid] = x[((size_t)(b * 32 + gi * 2 + pr) * 32 + (gj * 2 + pc)) * 4 + ci];
    }
    __syncthreads();
    #pragma unroll
    for (int cc = 0; cc < 3; ++cc) {
        const int col = cc * 256 + tid;
        float acc = pb[col];
        #pragma unroll
        for (int i = 0; i < 16; ++i) acc += pv[i] * pw[(size_t)i * HID + col];
        const int d4 = (col < 384) ? col : col - 384;   // 384 not pow2 -> no masking
        const int pos = (col < 384) ? gi : gj;
        const float kf = (float)(d4 < 192 ? d4 : d4 - 192);
        const float om = __expf(kf * (-9.210340371976184f / 192.f));
        const float a = (float)pos * om;
        acc += (d4 < 192) ? sinf(a) : cosf(a);
        h[(size_t)row * HID + col] = acc;
    }
}

// ---------------------------------------------------------------------------
// Kernel 5: weight convert fp32[K,N] -> bf16 transposed [N,K] (+ qkv bias pack)
// vectorized ushort2 transposed writes.
// ---------------------------------------------------------------------------
__global__ __launch_bounds__(256) void convert_weights(
    const float* __restrict__ q_w, const float* __restrict__ k_w,
    const float* __restrict__ v_w, const float* __restrict__ o_w,
    const float* __restrict__ fc1_w, const float* __restrict__ fc2_w,
    const float* __restrict__ q_b, const float* __restrict__ k_b,
    const float* __restrict__ v_b,
    unsigned short* __restrict__ wbase, size_t slot_stride,
    float* __restrict__ cbias, int first_layer)
{
    const int bid = blockIdx.x;
    const int l = first_layer + bid / 6913;
    const int t = bid % 6913;
    unsigned short* dst = wbase + (size_t)(bid / 6913) * slot_stride;
    const int tid = threadIdx.x;
    if (t == 6912) {
        float* cb = cbias + (size_t)l * 2304;
        for (int i = tid; i < 2304; i += 256) {
            float v;
            if (i < 768)       v = q_b[(size_t)l * 768 + i];
            else if (i < 1536) v = k_b[(size_t)l * 768 + i - 768];
            else               v = v_b[(size_t)l * 768 + i - 1536];
            cb[i] = v;
        }
        return;
    }
    const float* src; int srcN; unsigned short* d; int dLd; int tr, tc;
    if (t < 2304) {
        const int mat = t / 576, tt = t % 576; tr = tt / 24; tc = tt % 24;
        srcN = 768; dLd = 768;
        if (mat == 0)      { src = q_w + (size_t)l * 589824; d = dst; }
        else if (mat == 1) { src = k_w + (size_t)l * 589824; d = dst + 589824; }
        else if (mat == 2) { src = v_w + (size_t)l * 589824; d = dst + 1179648; }
        else               { src = o_w + (size_t)l * 589824; d = dst + 1769472; }
    } else if (t < 4608) {
        const int tt = t - 2304; tr = tt / 96; tc = tt % 96;
        src = fc1_w + (size_t)l * 2359296; srcN = 3072; dLd = 768; d = dst + 2359296;
    } else {
        const int tt = t - 4608; tr = tt / 24; tc = tt % 24;
        src = fc2_w + (size_t)l * 2359296; srcN = 768; dLd = 3072; d = dst + 4718592;
    }
    __shared__ float lt[32][33];
    const int tx = tid & 31, ty = tid >> 5;
    const int r0 = tr * 32, c0 = tc * 32;
    #pragma unroll
    for (int i = 0; i < 4; ++i)
        lt[ty + i * 8][tx] = src[(size_t)(r0 + ty + i * 8) * srcN + c0 + tx];
    __syncthreads();
    const int q = tid & 15;          // row-pair index (rows 2q, 2q+1)
    const int cw = tid >> 4;         // 16 cols per pass
    #pragma unroll
    for (int i = 0; i < 2; ++i) {
        const int cc = cw + i * 16;
        const unsigned int pk = (unsigned int)f2bf(lt[2 * q][cc])
                              | ((unsigned int)f2bf(lt[2 * q + 1][cc]) << 16);
        *(unsigned int*)&d[(size_t)(c0 + cc) * dLd + r0 + 2 * q] = pk;
    }
}

// ---------------------------------------------------------------------------
// Kernel 6: LayerNorm (no affine) + adaLN modulate -> bf16.
// grid 2048, 4 rows/block, 192 thr, float4 io.
// ---------------------------------------------------------------------------
__global__ __launch_bounds__(192) void ln_mod(const float* __restrict__ hbuf,
                                              const float* __restrict__ mod,
                                              int sh_off, int sc_off, int mld,
                                              unsigned short* __restrict__ xout)
{
    const int tid = threadIdx.x;
    __shared__ float sb[3], ssb[3];
    #pragma unroll
    for (int rr = 0; rr < 4; ++rr) {
        const int row = blockIdx.x * 4 + rr;
        const float4 xv = *(const float4*)&hbuf[(size_t)row * HID + tid * 4];
        float s = (xv.x + xv.y) + (xv.z + xv.w);
        float ss = (xv.x * xv.x + xv.y * xv.y) + (xv.z * xv.z + xv.w * xv.w);
        #pragma unroll
        for (int d = 1; d < 64; d <<= 1) { s += __shfl_xor(s, d); ss += __shfl_xor(ss, d); }
        if ((tid & 63) == 0) { sb[tid >> 6] = s; ssb[tid >> 6] = ss; }
        __syncthreads();
        s = sb[0] + sb[1] + sb[2];
        ss = ssb[0] + ssb[1] + ssb[2];
        const float mean = s * (1.f / 768.f);
        const float var = ss * (1.f / 768.f) - mean * mean;
        const float rs = rsqrtf(var + 1e-5f);
        const int b = row >> 8;
        const float* mrow = mod + (size_t)b * mld;
        const float4 sc = *(const float4*)&mrow[sc_off + tid * 4];
        const float4 sh = *(const float4*)&mrow[sh_off + tid * 4];
        ushort4 o;
        o.x = f2bf((xv.x - mean) * rs * (1.f + sc.x) + sh.x);
        o.y = f2bf((xv.y - mean) * rs * (1.f + sc.y) + sh.y);
        o.z = f2bf((xv.z - mean) * rs * (1.f + sc.z) + sh.z);
        o.w = f2bf((xv.w - mean) * rs * (1.f + sc.w) + sh.w);
        *(ushort4*)&xout[(size_t)row * HID + tid * 4] = o;
        __syncthreads();   // protect sb/ssb before next row's write
    }
}

// ---------------------------------------------------------------------------
// Kernel 7: bf16 MFMA GEMM, C = A[M,K] @ B[K,N] (+epilogues), B given as [N,K].
// Tile 128M x BN, BK in {32,64}, 4 waves (2x2), 16x16x32 MFMA.
// global_load_lds width-16 staging + LDS double-buffer, 1 barrier/K-step.
// BK=64 (BN=64 kernels: o, fc2): halves barrier/drain count (fc2 96->48,
// o 24->12); LDS 24->48 KB, still 3 blocks/CU (grid-limited). qkv/fc1 keep
// BK=32 (BN=128 at BK=64 would be 64 KB -> 2/CU, the measured-bad m132 regime).
// T1: bijective XCD swizzle (grids all %8==0).
// EPI 0: bf16(acc+bias) ; EPI 1: bf16(gelu_exact(acc+bias)) ;
// EPI 2: h += gate[b][col]*(acc+bias)
// ---------------------------------------------------------------------------
template<int EPI, int BN, int BK, int RT>
__global__ __launch_bounds__(256) void gemm_bt(const unsigned short* __restrict__ A,
                                               const unsigned short* __restrict__ Bt,
                                               const float* __restrict__ bias,
                                               void* __restrict__ outp,
                                               const float* __restrict__ gate,
                                               int K, int ldo)
{
    constexpr int AELEMS = 128 * BK;
    constexpr int BELEMS = BN * BK;
    constexpr int GA = AELEMS / 2048;            // A granules per thread
    constexpr int GB = BELEMS / 2048;            // B granules per thread
    constexpr int NJ = BN / 32;
    constexpr int KK = BK / 32;
    __shared__ unsigned short sAB[2][AELEMS + BELEMS];
    const int tid = threadIdx.x;
    const int lane = tid & 63;
    const int w = tid >> 6;
    const int wm = w >> 1, wn = w & 1;
    const int nwg = gridDim.x * gridDim.y;
    int bidl = blockIdx.y * gridDim.x + blockIdx.x;
    bidl = (bidl & 7) * (nwg >> 3) + (bidl >> 3);
    const int bx = bidl % gridDim.x, by = bidl / gridDim.x;
    const int rowbase = by << 7;
    const int colbase = bx * BN;
    const size_t aStep = (size_t)(gridDim.y << 7) * K;   // row-tile stride (RT>1)
    size_t aOff[GA], bOff[GB];
    #pragma unroll
    for (int i = 0; i < GA; ++i) {
        const int off = (i * 256 + tid) * 8;
        aOff[i] = (size_t)(rowbase + off / BK) * K + (off % BK);
    }
    #pragma unroll
    for (int i = 0; i < GB; ++i) {
        const int off = (i * 256 + tid) * 8;
        bOff[i] = (size_t)(colbase + off / BK) * K + (off % BK);
    }
    const int ldsw = w * 512;                    // wave-uniform granule sub-base
    f32x4 acc[4][NJ];
    #pragma unroll
    for (int i = 0; i < 4; ++i)
        #pragma unroll
        for (int j = 0; j < NJ; ++j) acc[i][j] = (f32x4){0.f, 0.f, 0.f, 0.f};
    const int nk = K / BK;
    const int lm = lane & 15, lg = lane >> 4;
    auto stage = [&](unsigned short* base, int kt, int rt_) {
        const size_t ash = (size_t)rt_ * aStep + (size_t)kt * BK;
        const size_t bsh = (size_t)kt * BK;
        #pragma unroll
        for (int i = 0; i < GA; ++i)
            gload16(A + aOff[i] + ash, base + i * 2048 + ldsw);
        #pragma unroll
        for (int i = 0; i < GB; ++i)
            gload16(Bt + bOff[i] + bsh, base + AELEMS + i * 2048 + ldsw);
    };
    stage(&sAB[0][0], 0, 0);
    __syncthreads();
    int cur = 0;
    #pragma unroll
    for (int rt = 0; rt < RT; ++rt) {
        for (int kt = 0; kt < nk; ++kt) {
            if (kt + 1 < nk)          stage(&sAB[cur ^ 1][0], kt + 1, rt);
            else if (rt + 1 < RT)     stage(&sAB[cur ^ 1][0], 0, rt + 1);
            const unsigned short* sAc = &sAB[cur][0];
            const unsigned short* sBc = &sAB[cur][AELEMS];
            s16x8 af[KK][4], bfr[KK][NJ];
            #pragma unroll
            for (int kk = 0; kk < KK; ++kk) {
                #pragma unroll
                for (int mi = 0; mi < 4; ++mi)
                    af[kk][mi] = *(const s16x8*)&sAc[(wm * 64 + mi * 16 + lm) * BK + kk * 32 + lg * 8];
                #pragma unroll
                for (int nj = 0; nj < NJ; ++nj)
                    bfr[kk][nj] = *(const s16x8*)&sBc[(wn * (16 * NJ) + nj * 16 + lm) * BK + kk * 32 + lg * 8];
            }
            #pragma unroll
            for (int kk = 0; kk < KK; ++kk)
                #pragma unroll
                for (int mi = 0; mi < 4; ++mi)
                    #pragma unroll
                    for (int nj = 0; nj < NJ; ++nj)
                        acc[mi][nj] = __builtin_amdgcn_mfma_f32_16x16x32_bf16(af[kk][mi], bfr[kk][nj], acc[mi][nj], 0, 0, 0);
            __syncthreads();   // drains this iter's global_load_lds
            cur ^= 1;
        }
        // epilogue for this row-tile
        const int rowb = rowbase + rt * (gridDim.y << 7);
        float bv[NJ], gv[NJ];
        #pragma unroll
        for (int nj = 0; nj < NJ; ++nj) {
            const int col = colbase + wn * (16 * NJ) + nj * 16 + lm;
            bv[nj] = bias[col];
            if constexpr (EPI == 2) gv[nj] = gate[(size_t)(rowb >> 8) * ADA_LD + col];
        }
        #pragma unroll
        for (int mi = 0; mi < 4; ++mi) {
            const int row = rowb + wm * 64 + mi * 16 + (lg << 2);
            #pragma unroll
            for (int nj = 0; nj < NJ; ++nj) {
                const int col = colbase + wn * (16 * NJ) + nj * 16 + lm;
                #pragma unroll
                for (int r = 0; r < 4; ++r) {
                    const float v = acc[mi][nj][r] + bv[nj];
                    if constexpr (EPI == 0) {
                        ((unsigned short*)outp)[(size_t)(row + r) * ldo + col] = f2bf(v);
                    } else if constexpr (EPI == 1) {
                        const float g = 0.5f * v * (1.f + erff(v * 0.70710678118654752f));
                        ((unsigned short*)outp)[(size_t)(row + r) * ldo + col] = f2bf(g);
                    } else {
                        float* O = (float*)outp;
                        const size_t idx = (size_t)(row + r) * ldo + col;
                        O[idx] = O[idx] + gv[nj] * v;
                    }
                }
            }
        }
        if (rt + 1 < RT) {
            #pragma unroll
            for (int i = 0; i < 4; ++i)
                #pragma unroll
                for (int j = 0; j < NJ; ++j) acc[i][j] = (f32x4){0.f, 0.f, 0.f, 0.f};
        }
    }
}

// ---------------------------------------------------------------------------
// Kernel 8: fused attention (4 waves x 32 q-rows, T5 setprio).
// ---------------------------------------------------------------------------
__global__ __launch_bounds__(256) void attn_fused(const unsigned short* __restrict__ qkv,
                                                  unsigned short* __restrict__ yv)
{
    __shared__ unsigned short Vt[64][264];
    __shared__ unsigned short Psm[4][32 * 72];
    __shared__ float Ssc[4][32];
    const int bid = blockIdx.x;
    const int b = bid / 24, rem = bid % 24, h = rem >> 1, half = rem & 1;
    const int tid = threadIdx.x, w = tid >> 6, lane = tid & 63;
    {
        const int dhg = tid & 7, tk = tid >> 3;
        #pragma unroll
        for (int g = 0; g < 8; ++g) {
            const int tok = tk + g * 32;
            s16x8 vv = *(const s16x8*)(qkv + (size_t)(b * 256 + tok) * 2304 + 1536 + h * 64 + dhg * 8);
            #pragma unroll
            for (int j = 0; j < 8; ++j) Vt[dhg * 8 + j][tok] = (unsigned short)vv[j];
        }
    }
    __syncthreads();
    const int q0 = half * 128 + w * 32;
    const int lm = lane & 15, lg = lane >> 4;
    const unsigned short* Qb = qkv + (size_t)(b * 256 + q0) * 2304 + h * 64;
    s16x8 qf[2][2];
    #pragma unroll
    for (int ni = 0; ni < 2; ++ni)
        #pragma unroll
        for (int kk = 0; kk < 2; ++kk)
            qf[ni][kk] = *(const s16x8*)(Qb + (size_t)(ni * 16 + lm) * 2304 + kk * 32 + lg * 8);
    f32x4 o_[2][4];
    #pragma unroll
    for (int i = 0; i < 2; ++i)
        #pragma unroll
        for (int j = 0; j < 4; ++j) o_[i][j] = (f32x4){0.f, 0.f, 0.f, 0.f};
    float m_[2], l_[2];
    #pragma unroll
    for (int i = 0; i < 2; ++i) { m_[i] = -1e30f; l_[i] = 0.f; }
    const float s3 = 0.57735026918962576f;   // 1/sqrt(3)
    for (int c = 0; c < 4; ++c) {
        f32x4 st[4][2];
        #pragma unroll
        for (int i = 0; i < 4; ++i)
            #pragma unroll
            for (int j = 0; j < 2; ++j) st[i][j] = (f32x4){0.f, 0.f, 0.f, 0.f};
        const unsigned short* Kb = qkv + (size_t)(b * 256 + c * 64) * 2304 + 768 + h * 64;
        __builtin_amdgcn_s_setprio(1);
        #pragma unroll
        for (int kk = 0; kk < 2; ++kk)
            #pragma unroll
            for (int mi = 0; mi < 4; ++mi) {
                const s16x8 kf = *(const s16x8*)(Kb + (size_t)(mi * 16 + lm) * 2304 + kk * 32 + lg * 8);
                #pragma unroll
                for (int ni = 0; ni < 2; ++ni)
                    st[mi][ni] = __builtin_amdgcn_mfma_f32_16x16x32_bf16(kf, qf[ni][kk], st[mi][ni], 0, 0, 0);
            }
        __builtin_amdgcn_s_setprio(0);
        #pragma unroll
        for (int ni = 0; ni < 2; ++ni) {
            float cm = -1e30f;
            #pragma unroll
            for (int mi = 0; mi < 4; ++mi)
                #pragma unroll
                for (int r = 0; r < 4; ++r) cm = fmaxf(cm, st[mi][ni][r]);
            cm = fmaxf(cm, __shfl_xor(cm, 16));
            cm = fmaxf(cm, __shfl_xor(cm, 32));
            cm *= s3;
            const float mn = fmaxf(m_[ni], cm);
            const float corr = __expf(m_[ni] - mn);
            float cs = 0.f;
            #pragma unroll
            for (int mi = 0; mi < 4; ++mi) {
                float p0 = __expf(st[mi][ni][0] * s3 - mn);
                float p1 = __expf(st[mi][ni][1] * s3 - mn);
                float p2 = __expf(st[mi][ni][2] * s3 - mn);
                float p3 = __expf(st[mi][ni][3] * s3 - mn);
                cs += (p0 + p1) + (p2 + p3);
                uint2 pk;
                pk.x = (unsigned int)f2bf(p0) | ((unsigned int)f2bf(p1) << 16);
                pk.y = (unsigned int)f2bf(p2) | ((unsigned int)f2bf(p3) << 16);
                *(uint2*)&Psm[w][(ni * 16 + lm) * 72 + mi * 16 + lg * 4] = pk;
            }
            cs += __shfl_xor(cs, 16);
            cs += __shfl_xor(cs, 32);
            l_[ni] = l_[ni] * corr + cs;
            m_[ni] = mn;
            if (lane < 16) Ssc[w][ni * 16 + lane] = corr;
        }
        asm volatile("" ::: "memory");
        #pragma unroll
        for (int qi = 0; qi < 2; ++qi) {
            float fr[4];
            #pragma unroll
            for (int r = 0; r < 4; ++r) fr[r] = Ssc[w][qi * 16 + lg * 4 + r];
            #pragma unroll
            for (int di = 0; di < 4; ++di)
                #pragma unroll
                for (int r = 0; r < 4; ++r) o_[qi][di][r] *= fr[r];
        }
        __builtin_amdgcn_s_setprio(1);
        #pragma unroll
        for (int kk = 0; kk < 2; ++kk)
            #pragma unroll
            for (int qi = 0; qi < 2; ++qi) {
                const s16x8 pa = *(const s16x8*)&Psm[w][(qi * 16 + lm) * 72 + kk * 32 + lg * 8];
                #pragma unroll
                for (int di = 0; di < 4; ++di) {
                    const s16x8 vb = *(const s16x8*)&Vt[di * 16 + lm][c * 64 + kk * 32 + lg * 8];
                    o_[qi][di] = __builtin_amdgcn_mfma_f32_16x16x32_bf16(pa, vb, o_[qi][di], 0, 0, 0);
                }
            }
        __builtin_amdgcn_s_setprio(0);
    }
    asm volatile("" ::: "memory");
    if (lane < 16) {
        #pragma unroll
        for (int ni = 0; ni < 2; ++ni) Ssc[w][ni * 16 + lane] = 1.f / l_[ni];
    }
    asm volatile("" ::: "memory");
    #pragma unroll
    for (int qi = 0; qi < 2; ++qi) {
        float fr[4];
        #pragma unroll
        for (int r = 0; r < 4; ++r) fr[r] = Ssc[w][qi * 16 + lg * 4 + r];
        #pragma unroll
        for (int di = 0; di < 4; ++di)
            #pragma unroll
            for (int r = 0; r < 4; ++r) {
                const float val = o_[qi][di][r] * fr[r];
                yv[(size_t)(b * 256 + q0 + qi * 16 + lg * 4 + r) * HID + h * 64 + di * 16 + lm] = f2bf(val);
            }
    }
}

// ---------------------------------------------------------------------------
// Kernel 9: final projection  out[8192,16] = xn @ fin_w[768,16] + fin_b
// ---------------------------------------------------------------------------
__global__ __launch_bounds__(256) void fin_gemm(const unsigned short* __restrict__ xn,
                                                const float* __restrict__ w,
                                                const float* __restrict__ bias,
                                                float* __restrict__ out)
{
    __shared__ unsigned short xs[16 * 768];
    const int rb = blockIdx.x * 16, tid = threadIdx.x;
    #pragma unroll
    for (int i = 0; i < 6; ++i) {
        const int v = tid + i * 256;
        const int row = v / 96, koff = (v % 96) * 8;
        *(s16x8*)&xs[v * 8] = *(const s16x8*)(xn + (size_t)(rb + row) * HID + koff);
    }
    __syncthreads();
    const int r = tid >> 4, o = tid & 15;
    float acc = bias[o];
    #pragma unroll 8
    for (int k = 0; k < 768; ++k) acc += bf2f(xs[r * 768 + k]) * w[(size_t)k * 16 + o];
    out[(size_t)(rb + r) * 16 + o] = acc;
}

// ---------------------------------------------------------------------------
// Host launcher
// ---------------------------------------------------------------------------
extern "C" void kernel_launch(void* const* d_in, const int* in_sizes, int n_in,
                              void* d_out, int out_size, void* d_ws, size_t ws_size,
                              hipStream_t stream)
{
    const float* x        = (const float*)d_in[0];
    const float* t        = (const float*)d_in[1];
    const int*   y        = (const int*)d_in[2];
    const float* patch_w  = (const float*)d_in[3];
    const float* patch_b  = (const float*)d_in[4];
    const float* t_w1     = (const float*)d_in[5];
    const float* t_b1     = (const float*)d_in[6];
    const float* t_w2     = (const float*)d_in[7];
    const float* t_b2     = (const float*)d_in[8];
    const float* label_e  = (const float*)d_in[9];
    const float* ada_w    = (const float*)d_in[10];
    const float* ada_b    = (const float*)d_in[11];
    const float* q_w      = (const float*)d_in[12];
    const float* q_b      = (const float*)d_in[13];
    const float* k_w      = (const float*)d_in[14];
    const float* k_b      = (const float*)d_in[15];
    const float* v_w      = (const float*)d_in[16];
    const float* v_b      = (const float*)d_in[17];
    const float* o_w      = (const float*)d_in[18];
    const float* o_b      = (const float*)d_in[19];
    const float* fc1_w    = (const float*)d_in[20];
    const float* fc1_b    = (const float*)d_in[21];
    const float* fc2_w    = (const float*)d_in[22];
    const float* fc2_b    = (const float*)d_in[23];
    const float* fada_w   = (const float*)d_in[24];
    const float* fada_b   = (const float*)d_in[25];
    const float* fin_w    = (const float*)d_in[26];
    const float* fin_b    = (const float*)d_in[27];

    char* ws = (char*)d_ws;
    size_t off = 0;
    auto alloc = [&](size_t bytes) { size_t o = off; off = (off + bytes + 255) & ~(size_t)255; return o; };
    const size_t OFF_H     = alloc((size_t)ROWS * HID * 4);
    const size_t OFF_XN    = alloc((size_t)ROWS * HID * 2);
    const size_t OFF_QKV   = alloc((size_t)ROWS * 2304 * 2);
    const size_t OFF_YV    = alloc((size_t)ROWS * HID * 2);
    const size_t OFF_MLP   = alloc((size_t)ROWS * MLPD * 2);
    const size_t OFF_ADA   = alloc((size_t)12 * 32 * ADA_LD * 4);
    const size_t OFF_FADA  = alloc((size_t)32 * 1536 * 4);
    const size_t OFF_Z2    = alloc((size_t)32 * HID * 4);
    const size_t OFF_Z1    = alloc((size_t)32 * HID * 4);
    const size_t OFF_CB    = alloc((size_t)12 * 2304 * 4);
    const size_t OFF_CBF   = alloc((size_t)32 * HID * 2);
    const size_t OFF_W     = off;
    const size_t WSLOT_ELEMS = 7077888;  // per-layer bf16 weight elems
    const bool big = (ws_size >= OFF_W + (size_t)12 * WSLOT_ELEMS * 2);

    float*          h     = (float*)(ws + OFF_H);
    unsigned short* xn    = (unsigned short*)(ws + OFF_XN);
    unsigned short* qkv   = (unsigned short*)(ws + OFF_QKV);
    unsigned short* yv    = (unsigned short*)(ws + OFF_YV);
    unsigned short* mlp   = (unsigned short*)(ws + OFF_MLP);
    float*          adaA  = (float*)(ws + OFF_ADA);
    float*          fada  = (float*)(ws + OFF_FADA);
    float*          z2    = (float*)(ws + OFF_Z2);
    float*          z1    = (float*)(ws + OFF_Z1);
    float*          cbias = (float*)(ws + OFF_CB);
    unsigned short* cactb = (unsigned short*)(ws + OFF_CBF);
    unsigned short* wsW   = (unsigned short*)(ws + OFF_W);

    // startup: conditioning chain, ada, patch, weight convert
    if (big) {
        ada_init<<<3, 256, 0, stream>>>(ada_b, fada_b, t_b1, t_b2, label_e, y,
                                        adaA, fada, z1, z2, 222);
    } else {
        ada_init<<<225, 256, 0, stream>>>(ada_b, fada_b, t_b1, t_b2, label_e, y,
                                          adaA, fada, z1, z2, 0);
    }
    temb1_k<<<dim3(32, 3, 2), 256, 0, stream>>>(t, t_w1, z1);
    temb2_k<<<dim3(32, 3, 4), 256, 0, stream>>>(z1, t_w2, z2);
    if (big) {
        csilu_k<<<12, 256, 0, stream>>>(z2, cactb);
        ada_mfma<<<222, 256, 0, stream>>>(cactb, ada_w, fada_w, ada_b, fada_b, adaA, fada);
        convert_weights<<<6913 * 12, 256, 0, stream>>>(q_w, k_w, v_w, o_w, fc1_w, fc2_w,
                                                       q_b, k_b, v_b, wsW, WSLOT_ELEMS, cbias, 0);
    } else {
        ada_gemm2<<<dim3(222, 8), 256, 0, stream>>>(z2, ada_w, fada_w, adaA, fada);
    }
    patch_embed<<<8192, 256, 0, stream>>>(x, patch_w, patch_b, h);

    for (int l = 0; l < 12; ++l) {
        unsigned short* wslot = wsW + (big ? (size_t)l * WSLOT_ELEMS : 0);
        if (!big) {
            convert_weights<<<6913, 256, 0, stream>>>(q_w, k_w, v_w, o_w, fc1_w, fc2_w,
                                                      q_b, k_b, v_b, wslot, 0, cbias, l);
        }
        unsigned short* qkvT = wslot;
        unsigned short* oT   = wslot + 1769472;
        unsigned short* f1T  = wslot + 2359296;
        unsigned short* f2T  = wslot + 4718592;
        float* ada_l  = adaA + (size_t)l * 32 * ADA_LD;
        float* cb_l   = cbias + (size_t)l * 2304;

        ln_mod<<<2048, 192, 0, stream>>>(h, ada_l, 0, 768, ADA_LD, xn);
        gemm_bt<0, 128, 32, 1><<<dim3(18, 64), 256, 0, stream>>>(xn, qkvT, cb_l, qkv, nullptr, 768, 2304);
        attn_fused<<<768, 256, 0, stream>>>(qkv, yv);
        // o-proj: BK=64 -> 12 K-steps (was 24), 48 KB LDS, 3 blocks/CU
        gemm_bt<2, 64, 64, 1><<<dim3(12, 64), 256, 0, stream>>>(yv, oT, o_b + (size_t)l * 768, h,
                                                                ada_l + 1536, 768, 768);
        ln_mod<<<2048, 192, 0, stream>>>(h, ada_l, 2304, 3072, ADA_LD, xn);
        gemm_bt<1, 128, 32, 1><<<dim3(24, 64), 256, 0, stream>>>(xn, f1T, fc1_b + (size_t)l * 3072, mlp,
                                                                 nullptr, 768, 3072);
        // fc2: BK=64 -> 48 K-steps (was 96), halved barrier drains
        gemm_bt<2, 64, 64, 1><<<dim3(12, 64), 256, 0, stream>>>(mlp, f2T, fc2_b + (size_t)l * 768, h,
                                                                ada_l + 3840, 3072, 768);
    }

    // final layer
    ln_mod<<<2048, 192, 0, stream>>>(h, fada, 0, 768, 1536, xn);
    fin_gemm<<<512, 256, 0, stream>>>(xn, fin_w, fin_b, (float*)d_out);
}